// Round 8
// baseline (431.131 us; speedup 1.0000x reference)
//
#include <hip/hip_runtime.h>
#include <hip/hip_bf16.h>
#include <hip/hip_fp16.h>
#include <math.h>

// ---------------------------------------------------------------------------
// 2-layer GAT (PyG GATConv, concat=False, add_self_loops=True) on MI355X.
// R8 (= R7 + compile fix): per-edge softmax weights precomputed once
// (edge_w_kernel, fp16 pairs, stored as u64) instead of 32x-replicated exp in
// node_kernel. Node inner loop: broadcast srcidx + weight dword, one Hb
// gather, 2 fma. Scatter also emits edst.
// ---------------------------------------------------------------------------

__device__ __forceinline__ float lrelu(float x) { return x > 0.f ? x : 0.2f * x; }

// Monotone float<->uint encoding for atomicMax over signed floats.
// fenc(-FLT_MAX) > 0, so memset-0 acts as a -inf sentinel.
__device__ __forceinline__ unsigned int fenc(float f) {
    unsigned int u = __float_as_uint(f);
    return (u & 0x80000000u) ? ~u : (u | 0x80000000u);
}
__device__ __forceinline__ float fdec(unsigned int e) {
    unsigned int u = (e & 0x80000000u) ? (e & 0x7FFFFFFFu) : ~e;
    return __uint_as_float(u);
}

// bf16 round-to-nearest-even pack/unpack
__device__ __forceinline__ unsigned short f2bf(float x) {
    unsigned u = __float_as_uint(x);
    return (unsigned short)((u + 0x7FFFu + ((u >> 16) & 1u)) >> 16);
}
__device__ __forceinline__ float bflo(unsigned w) { return __uint_as_float(w << 16); }
__device__ __forceinline__ float bfhi(unsigned w) { return __uint_as_float(w & 0xFFFF0000u); }

// fp16 pack/unpack via bit ops
__device__ __forceinline__ unsigned pack_h2(float a, float b) {
    const __half2 h = __float22half2_rn(make_float2(a, b));
    return *(const unsigned*)&h;
}
__device__ __forceinline__ float2 unpack_h2(unsigned w) {
    __half2 h = *(const __half2*)&w;
    return __half22float2(h);
}

// ---------------- hierarchical scan (CSR rowptr + cursor) ----------------
__global__ __launch_bounds__(256) void scan_part(const int* __restrict__ cnt,
                                                 int* __restrict__ bsum, int n) {
    __shared__ int red[256];
    const int t = threadIdx.x;
    const int i = blockIdx.x * 256 + t;
    red[t] = (i < n) ? cnt[i] : 0;
    __syncthreads();
    for (int o = 128; o > 0; o >>= 1) {
        if (t < o) red[t] += red[t + o];
        __syncthreads();
    }
    if (t == 0) bsum[blockIdx.x] = red[0];
}

__global__ __launch_bounds__(256) void scan_mid(const int* __restrict__ bsum,
                                                int* __restrict__ boff, int nb,
                                                int* __restrict__ rowptr, int n) {
    __shared__ int s[256];
    const int t = threadIdx.x;
    const int v = (t < nb) ? bsum[t] : 0;
    s[t] = v;
    __syncthreads();
    for (int o = 1; o < 256; o <<= 1) {
        const int u = (t >= o) ? s[t - o] : 0;
        __syncthreads();
        s[t] += u;
        __syncthreads();
    }
    if (t < nb) boff[t] = s[t] - v;   // exclusive block offset
    if (t == 255) rowptr[n] = s[255]; // total
}

__global__ __launch_bounds__(256) void scan_final(const int* __restrict__ cnt,
                                                  const int* __restrict__ boff,
                                                  int* __restrict__ rowptr,
                                                  int* __restrict__ cursor, int n) {
    __shared__ int s[256];
    const int t = threadIdx.x;
    const int i = blockIdx.x * 256 + t;
    const int v = (i < n) ? cnt[i] : 0;
    s[t] = v;
    __syncthreads();
    for (int o = 1; o < 256; o <<= 1) {
        const int u = (t >= o) ? s[t - o] : 0;
        __syncthreads();
        s[t] += u;
        __syncthreads();
    }
    if (i < n) {
        const int ex = boff[blockIdx.x] + s[t] - v;
        rowptr[i] = ex;
        cursor[i] = ex;
    }
}

// ---------------- bucketed scatter (int4-vectorized) ----------------
// Bucket b handled only by blocks with blockIdx%8==b (XCD-affine).
// Stores src*16 and dst*16 (byte offsets into 16B-row tables).
__global__ __launch_bounds__(256) void scatter_kernel(
    const int* __restrict__ src, const int* __restrict__ dst,
    int* __restrict__ cursor, int* __restrict__ srcidx, int* __restrict__ edst,
    int E, int npb) {
    const int b = blockIdx.x & 7;
    const int gb = blockIdx.x >> 3;
    const int nbl = gridDim.x >> 3;
    const int lo = b * npb, hi = lo + npb;
    const int E4 = E >> 2;
    const int4* dst4 = (const int4*)dst;
    const int4* src4 = (const int4*)src;
    for (int i = gb * blockDim.x + threadIdx.x; i < E4; i += nbl * blockDim.x) {
        const int4 d = dst4[i];
        const int4 s = src4[i];
        if (d.x >= lo && d.x < hi) {
            const int p = atomicAdd(&cursor[d.x], 1);
            __builtin_nontemporal_store(s.x << 4, &srcidx[p]);
            __builtin_nontemporal_store(d.x << 4, &edst[p]);
        }
        if (d.y >= lo && d.y < hi) {
            const int p = atomicAdd(&cursor[d.y], 1);
            __builtin_nontemporal_store(s.y << 4, &srcidx[p]);
            __builtin_nontemporal_store(d.y << 4, &edst[p]);
        }
        if (d.z >= lo && d.z < hi) {
            const int p = atomicAdd(&cursor[d.z], 1);
            __builtin_nontemporal_store(s.z << 4, &srcidx[p]);
            __builtin_nontemporal_store(d.z << 4, &edst[p]);
        }
        if (d.w >= lo && d.w < hi) {
            const int p = atomicAdd(&cursor[d.w], 1);
            __builtin_nontemporal_store(s.w << 4, &srcidx[p]);
            __builtin_nontemporal_store(d.w << 4, &edst[p]);
        }
    }
    if (blockIdx.x == 0 && threadIdx.x < (E & 3)) {
        const int i = (E4 << 2) + threadIdx.x;
        const int d = dst[i];
        if (d >= lo && d < hi) {
            const int p = atomicAdd(&cursor[d], 1);
            __builtin_nontemporal_store(src[i] << 4, &srcidx[p]);
            __builtin_nontemporal_store(d << 4, &edst[p]);
        }
    }
}

// ---------------- per-edge softmax weights (fp16 pairs, u64 record) ----------------
// wq[i] = u64: low dword = half2(q_pos0,q_pos1), high dword = half2(q_pos2,q_pos3).
__global__ __launch_bounds__(256) void edge_w_kernel(
    const int* __restrict__ srcidx, const int* __restrict__ edst,
    const float* __restrict__ asrc, const float* __restrict__ adst,
    const unsigned int* __restrict__ gmax, unsigned long long* __restrict__ wq,
    int Etot) {
    const char* aB = (const char*)asrc;
    const char* dB = (const char*)adst;
    const float g0 = fdec(gmax[0]), g1 = fdec(gmax[1]);
    const float g2 = fdec(gmax[2]), g3 = fdec(gmax[3]);
    for (int i = blockIdx.x * blockDim.x + threadIdx.x; i < Etot;
         i += gridDim.x * blockDim.x) {
        const unsigned s16 = (unsigned)__builtin_nontemporal_load(&srcidx[i]);
        const unsigned d16 = (unsigned)__builtin_nontemporal_load(&edst[i]);
        const float4 as = *(const float4*)(aB + s16);
        const float4 ad = *(const float4*)(dB + d16);
        const float q0 = __expf(lrelu(as.x + ad.x) - lrelu(g0 + ad.x));
        const float q1 = __expf(lrelu(as.y + ad.y) - lrelu(g1 + ad.y));
        const float q2 = __expf(lrelu(as.z + ad.z) - lrelu(g2 + ad.z));
        const float q3 = __expf(lrelu(as.w + ad.w) - lrelu(g3 + ad.w));
        const unsigned lo = pack_h2(q0, q1);
        const unsigned hi = pack_h2(q2, q3);
        const unsigned long long rec = ((unsigned long long)hi << 32) | lo;
        __builtin_nontemporal_store(rec, &wq[i]);
    }
}

// ---------------- GEMM + alpha (+ fused hist + global head max) ----------------
// Hb layout (bf16): u16 idx = row*128 + (head&1)*64 + f*2 + (head>>1)
//   -> for lane (hp,f): one dword holds heads (hp, hp+2).
// asrc/adst layout: [row*4 + pos], pos(head) = [0,2,1,3] interleave.
template <int K>
__global__ __launch_bounds__(256) void gemm_hist(
    const float* __restrict__ X, const float* __restrict__ W,
    const float* __restrict__ AttS, const float* __restrict__ AttD,
    unsigned short* __restrict__ Hb, float* __restrict__ asrc, float* __restrict__ adst,
    unsigned int* __restrict__ gmax, int n, int gemmGrid,
    const int* __restrict__ dst, int* __restrict__ cnt, int E) {
    constexpr int KC = (K < 64) ? K : 64;
    __shared__ __align__(16) float Ws[KC * 128];
    __shared__ __align__(16) float Xs[32 * K];
    __shared__ unsigned int smax[4];
    const int tid = threadIdx.x;

    if (blockIdx.x >= gemmGrid) {
        // ---- hist role ----
        const int hb = blockIdx.x - gemmGrid;
        const int histBlocks = gridDim.x - gemmGrid;
        const int E4 = E >> 2;
        const int4* dst4 = (const int4*)dst;
        for (int i = hb * blockDim.x + tid; i < E4; i += histBlocks * blockDim.x) {
            const int4 d = dst4[i];
            atomicAdd(&cnt[d.x], 1);
            atomicAdd(&cnt[d.y], 1);
            atomicAdd(&cnt[d.z], 1);
            atomicAdd(&cnt[d.w], 1);
        }
        if (hb == 0 && tid < (E & 3)) atomicAdd(&cnt[dst[(E4 << 2) + tid]], 1);
        return;
    }

    // ---- gemm role ----
    const int r = tid >> 5;          // row-in-batch 0..7
    const int sub = tid & 31;
    const int c0 = sub * 4;          // output col base (0..124)
    const int head = sub >> 3;       // 0..3
    const int pos = ((head & 1) << 1) | (head >> 1);  // [0,2,1,3] order
    const int fc = (sub & 7) * 4;    // feat-in-head base
    const int rowBase = blockIdx.x * 32;

    if (tid < 4) smax[tid] = 0u;
    {
        const float4* X4 = (const float4*)X;
        float4* Xs4 = (float4*)Xs;
        const int K4 = K / 4;
        for (int i = tid; i < 32 * K4; i += 256) {
            int rr = rowBase + i / K4;
            Xs4[i] = (rr < n) ? X4[(size_t)rr * K4 + (i % K4)] : make_float4(0.f, 0.f, 0.f, 0.f);
        }
    }

    float acc[4][4] = {};
    for (int kt = 0; kt < K; kt += KC) {
        __syncthreads();
        {
            const float4* W4 = (const float4*)(W + kt * 128);
            float4* Ws4 = (float4*)Ws;
            for (int i = tid; i < KC * 32; i += 256) Ws4[i] = W4[i];
        }
        __syncthreads();
        for (int k = 0; k < KC; ++k) {
            const float4 wv = *(const float4*)&Ws[k * 128 + c0];
#pragma unroll
            for (int b = 0; b < 4; ++b) {
                float xv = Xs[(b * 8 + r) * K + kt + k];
                acc[b][0] = fmaf(xv, wv.x, acc[b][0]);
                acc[b][1] = fmaf(xv, wv.y, acc[b][1]);
                acc[b][2] = fmaf(xv, wv.z, acc[b][2]);
                acc[b][3] = fmaf(xv, wv.w, acc[b][3]);
            }
        }
    }

    float a_s[4], a_d[4];
#pragma unroll
    for (int j = 0; j < 4; ++j) {
        a_s[j] = AttS[head * 32 + fc + j];
        a_d[j] = AttD[head * 32 + fc + j];
    }
    // u16 index pieces: row*128 + (head&1)*64 + f*2 + (head>>1)
    const unsigned hbase_head = (unsigned)(head & 1) * 64 + (unsigned)(head >> 1) + fc * 2;
#pragma unroll
    for (int b = 0; b < 4; ++b) {
        const int row = rowBase + b * 8 + r;
        if (row < n) {
            const unsigned hbase = (unsigned)row * 128 + hbase_head;
            Hb[hbase + 0] = f2bf(acc[b][0]);
            Hb[hbase + 2] = f2bf(acc[b][1]);
            Hb[hbase + 4] = f2bf(acc[b][2]);
            Hb[hbase + 6] = f2bf(acc[b][3]);
            float ps = acc[b][0] * a_s[0] + acc[b][1] * a_s[1] +
                       acc[b][2] * a_s[2] + acc[b][3] * a_s[3];
            float pd = acc[b][0] * a_d[0] + acc[b][1] * a_d[1] +
                       acc[b][2] * a_d[2] + acc[b][3] * a_d[3];
#pragma unroll
            for (int msk = 1; msk < 8; msk <<= 1) {
                ps += __shfl_xor(ps, msk);
                pd += __shfl_xor(pd, msk);
            }
            if ((sub & 7) == 0) {
                asrc[row * 4 + pos] = ps;
                adst[row * 4 + pos] = pd;
                atomicMax(&smax[pos], fenc(ps));
            }
        }
    }
    __syncthreads();
    if (tid < 4) atomicMax(&gmax[tid], smax[tid]);
}

// ---------------- per-node aggregate (weights precomputed) ----------------
// One node per 64-lane group; lane = hp*32 + f owns heads (hp, hp+2) -> one
// Hb dword. Per edge: broadcast srcidx + weight dword, 1 gather, 2 fma.
__global__ __launch_bounds__(256) void node_kernel(
    const int* __restrict__ rowptr, const int* __restrict__ srcidx,
    const unsigned short* __restrict__ Hb, const float* __restrict__ asrc,
    const float* __restrict__ adst, const unsigned int* __restrict__ gmax,
    const unsigned long long* __restrict__ wq, const float* __restrict__ bias,
    float* __restrict__ outp, int n, int apply_elu) {
    const int node = blockIdx.x * 4 + (threadIdx.x >> 6);
    if (node >= n) return;
    const int lane = threadIdx.x & 63;
    const unsigned f = lane & 31;
    const unsigned hp = lane >> 5;            // 0/1
    const unsigned hp8 = hp * 8;              // byte off into asrc/adst row (16B)
    const unsigned hp4 = hp * 4;              // byte off into wq record (8B)
    const unsigned hpf = hp * 128 + f * 4;    // byte off into Hb row (256B)
    const unsigned node16 = (unsigned)node * 16;
    const char* aB = (const char*)asrc;
    const char* dB = (const char*)adst;
    const char* hB = (const char*)Hb;
    const char* wB = (const char*)wq;

    const int beg = rowptr[node], end = rowptr[node + 1];
    const float2 ad01 = *(const float2*)(dB + node16 + hp8);
    const float2 M01 = make_float2(lrelu(fdec(gmax[hp * 2]) + ad01.x),
                                   lrelu(fdec(gmax[hp * 2 + 1]) + ad01.y));

    // self loop (fp32, same M as edge weights)
    const float2 aself = *(const float2*)(aB + node16 + hp8);
    float2 q = make_float2(__expf(lrelu(aself.x + ad01.x) - M01.x),
                           __expf(lrelu(aself.y + ad01.y) - M01.y));
    float2 s01 = q;
    const unsigned wSelf = *(const unsigned*)(hB + (node16 << 4) + hpf);
    float2 acc01 = make_float2(q.x * bflo(wSelf), q.y * bfhi(wSelf));

    int i = beg;
    for (; i + 16 <= end; i += 16) {
        unsigned sx[16];
#pragma unroll
        for (int u = 0; u < 16; ++u)
            sx[u] = (unsigned)__builtin_nontemporal_load(&srcidx[i + u]);  // s*16
        unsigned wv[16];
#pragma unroll
        for (int u = 0; u < 16; ++u)
            wv[u] = *(const unsigned*)(wB + (((unsigned)(i + u)) << 3) + hp4);
        unsigned w[16];
#pragma unroll
        for (int u = 0; u < 16; ++u) w[u] = *(const unsigned*)(hB + (sx[u] << 4) + hpf);
#pragma unroll
        for (int u = 0; u < 16; ++u) {
            const float2 qf = unpack_h2(wv[u]);
            s01.x += qf.x; s01.y += qf.y;
            acc01.x = fmaf(qf.x, bflo(w[u]), acc01.x);
            acc01.y = fmaf(qf.y, bfhi(w[u]), acc01.y);
        }
    }
    for (; i + 4 <= end; i += 4) {
        unsigned sx[4];
#pragma unroll
        for (int u = 0; u < 4; ++u)
            sx[u] = (unsigned)__builtin_nontemporal_load(&srcidx[i + u]);
        unsigned wv[4];
#pragma unroll
        for (int u = 0; u < 4; ++u)
            wv[u] = *(const unsigned*)(wB + (((unsigned)(i + u)) << 3) + hp4);
        unsigned w[4];
#pragma unroll
        for (int u = 0; u < 4; ++u) w[u] = *(const unsigned*)(hB + (sx[u] << 4) + hpf);
#pragma unroll
        for (int u = 0; u < 4; ++u) {
            const float2 qf = unpack_h2(wv[u]);
            s01.x += qf.x; s01.y += qf.y;
            acc01.x = fmaf(qf.x, bflo(w[u]), acc01.x);
            acc01.y = fmaf(qf.y, bfhi(w[u]), acc01.y);
        }
    }
    for (; i < end; ++i) {
        const unsigned sx = (unsigned)__builtin_nontemporal_load(&srcidx[i]);
        const unsigned wh = *(const unsigned*)(wB + (((unsigned)i) << 3) + hp4);
        const unsigned wv = *(const unsigned*)(hB + (sx << 4) + hpf);
        const float2 qf = unpack_h2(wh);
        s01.x += qf.x; s01.y += qf.y;
        acc01.x = fmaf(qf.x, bflo(wv), acc01.x);
        acc01.y = fmaf(qf.y, bfhi(wv), acc01.y);
    }

    float v = acc01.x / s01.x + acc01.y / s01.y;
    v += __shfl_xor(v, 32);     // add the other head pair
    v = v * 0.25f + bias[f];
    if (apply_elu) v = (v > 0.f) ? v : (__expf(v) - 1.f);
    if (lane < 32) outp[(size_t)node * 32 + f] = v;
}

// ---------------- launch ----------------

extern "C" void kernel_launch(void* const* d_in, const int* in_sizes, int n_in,
                              void* d_out, int out_size, void* d_ws, size_t ws_size,
                              hipStream_t stream) {
    const int N = in_sizes[0] / 128;
    const int E = in_sizes[1] / 2;
    const float* x = (const float*)d_in[0];
    const int* ei = (const int*)d_in[1];
    const float* W1 = (const float*)d_in[2];
    const float* atS1 = (const float*)d_in[3];
    const float* atD1 = (const float*)d_in[4];
    const float* b1 = (const float*)d_in[5];
    const float* W2 = (const float*)d_in[6];
    const float* atS2 = (const float*)d_in[7];
    const float* atD2 = (const float*)d_in[8];
    const float* b2 = (const float*)d_in[9];
    float* out = (float*)d_out;

    char* ws = (char*)d_ws;
    size_t off = 0;
    auto alloc = [&](size_t bytes) {
        void* p = ws + off;
        off = (off + bytes + 255) & ~(size_t)255;
        return p;
    };
    int* cnt = (int*)alloc((size_t)N * 4);
    unsigned int* gmax = (unsigned int*)alloc(8 * sizeof(unsigned int)); // [layer][pos]
    const size_t zeroBytes = off;  // cnt + gmax zeroed in one memset
    int* rowptr = (int*)alloc((size_t)(N + 1) * 4);
    int* cursor = (int*)alloc((size_t)N * 4);
    int* bsum = (int*)alloc(256 * 4);
    int* boff = (int*)alloc(256 * 4);
    int* srcidx = (int*)alloc((size_t)E * 4);
    int* edst = (int*)alloc((size_t)E * 4);
    unsigned long long* wq = (unsigned long long*)alloc((size_t)E * 8);
    unsigned short* hb = (unsigned short*)alloc((size_t)N * 128 * 2);  // packed bf16
    float* av_s = (float*)alloc((size_t)N * 4 * 4);
    float* av_d = (float*)alloc((size_t)N * 4 * 4);
    float* x2 = (float*)alloc((size_t)N * 32 * 4);

    const int* e_src = ei;
    const int* e_dst = ei + E;

    const int gemmGrid = (N + 31) / 32;
    const int histGrid = 1024;
    const int nodeGrid = (N + 3) / 4;
    const int npb = (N + 7) / 8;
    const int scanGrid = (N + 255) / 256;   // must be <= 256

    (void)hipMemsetAsync(cnt, 0, zeroBytes, stream);

    // layer 1
    gemm_hist<128><<<gemmGrid + histGrid, 256, 0, stream>>>(
        x, W1, atS1, atD1, hb, av_s, av_d, gmax, N, gemmGrid, e_dst, cnt, E);
    scan_part<<<scanGrid, 256, 0, stream>>>(cnt, bsum, N);
    scan_mid<<<1, 256, 0, stream>>>(bsum, boff, scanGrid, rowptr, N);
    scan_final<<<scanGrid, 256, 0, stream>>>(cnt, boff, rowptr, cursor, N);
    scatter_kernel<<<2048, 256, 0, stream>>>(e_src, e_dst, cursor, srcidx, edst, E, npb);
    edge_w_kernel<<<2048, 256, 0, stream>>>(srcidx, edst, av_s, av_d, gmax, wq, E);
    node_kernel<<<nodeGrid, 256, 0, stream>>>(rowptr, srcidx, hb, av_s, av_d, gmax,
                                              wq, b1, x2, N, 1);
    // layer 2
    gemm_hist<32><<<gemmGrid, 256, 0, stream>>>(
        x2, W2, atS2, atD2, hb, av_s, av_d, gmax + 4, N, gemmGrid, e_dst, cnt, E);
    edge_w_kernel<<<2048, 256, 0, stream>>>(srcidx, edst, av_s, av_d, gmax + 4, wq, E);
    node_kernel<<<nodeGrid, 256, 0, stream>>>(rowptr, srcidx, hb, av_s, av_d, gmax + 4,
                                              wq, b2, out, N, 0);
}

// Round 9
// 429.164 us; speedup vs baseline: 1.0046x; 1.0046x over previous
//
#include <hip/hip_runtime.h>
#include <hip/hip_bf16.h>
#include <hip/hip_fp16.h>
#include <math.h>

// ---------------------------------------------------------------------------
// 2-layer GAT (PyG GATConv, concat=False, add_self_loops=True) on MI355X.
// R9: scatter stores ONE u64 record per edge (src*16 | dst*16<<32), plain
// (non-nt) stores so bucketed slices coalesce in the XCD L2. edge_w/node read
// the packed record. Otherwise identical to R8.
// ---------------------------------------------------------------------------

__device__ __forceinline__ float lrelu(float x) { return x > 0.f ? x : 0.2f * x; }

// Monotone float<->uint encoding for atomicMax over signed floats.
// fenc(-FLT_MAX) > 0, so memset-0 acts as a -inf sentinel.
__device__ __forceinline__ unsigned int fenc(float f) {
    unsigned int u = __float_as_uint(f);
    return (u & 0x80000000u) ? ~u : (u | 0x80000000u);
}
__device__ __forceinline__ float fdec(unsigned int e) {
    unsigned int u = (e & 0x80000000u) ? (e & 0x7FFFFFFFu) : ~e;
    return __uint_as_float(u);
}

// bf16 round-to-nearest-even pack/unpack
__device__ __forceinline__ unsigned short f2bf(float x) {
    unsigned u = __float_as_uint(x);
    return (unsigned short)((u + 0x7FFFu + ((u >> 16) & 1u)) >> 16);
}
__device__ __forceinline__ float bflo(unsigned w) { return __uint_as_float(w << 16); }
__device__ __forceinline__ float bfhi(unsigned w) { return __uint_as_float(w & 0xFFFF0000u); }

// fp16 pack/unpack
__device__ __forceinline__ unsigned pack_h2(float a, float b) {
    const __half2 h = __float22half2_rn(make_float2(a, b));
    return *(const unsigned*)&h;
}
__device__ __forceinline__ float2 unpack_h2(unsigned w) {
    __half2 h = *(const __half2*)&w;
    return __half22float2(h);
}

// ---------------- hierarchical scan (CSR rowptr + cursor) ----------------
__global__ __launch_bounds__(256) void scan_part(const int* __restrict__ cnt,
                                                 int* __restrict__ bsum, int n) {
    __shared__ int red[256];
    const int t = threadIdx.x;
    const int i = blockIdx.x * 256 + t;
    red[t] = (i < n) ? cnt[i] : 0;
    __syncthreads();
    for (int o = 128; o > 0; o >>= 1) {
        if (t < o) red[t] += red[t + o];
        __syncthreads();
    }
    if (t == 0) bsum[blockIdx.x] = red[0];
}

__global__ __launch_bounds__(256) void scan_mid(const int* __restrict__ bsum,
                                                int* __restrict__ boff, int nb,
                                                int* __restrict__ rowptr, int n) {
    __shared__ int s[256];
    const int t = threadIdx.x;
    const int v = (t < nb) ? bsum[t] : 0;
    s[t] = v;
    __syncthreads();
    for (int o = 1; o < 256; o <<= 1) {
        const int u = (t >= o) ? s[t - o] : 0;
        __syncthreads();
        s[t] += u;
        __syncthreads();
    }
    if (t < nb) boff[t] = s[t] - v;   // exclusive block offset
    if (t == 255) rowptr[n] = s[255]; // total
}

__global__ __launch_bounds__(256) void scan_final(const int* __restrict__ cnt,
                                                  const int* __restrict__ boff,
                                                  int* __restrict__ rowptr,
                                                  int* __restrict__ cursor, int n) {
    __shared__ int s[256];
    const int t = threadIdx.x;
    const int i = blockIdx.x * 256 + t;
    const int v = (i < n) ? cnt[i] : 0;
    s[t] = v;
    __syncthreads();
    for (int o = 1; o < 256; o <<= 1) {
        const int u = (t >= o) ? s[t - o] : 0;
        __syncthreads();
        s[t] += u;
        __syncthreads();
    }
    if (i < n) {
        const int ex = boff[blockIdx.x] + s[t] - v;
        rowptr[i] = ex;
        cursor[i] = ex;
    }
}

// ---------------- bucketed scatter (int4-vectorized, single u64 store) -----
// Bucket b handled only by blocks with blockIdx%8==b (XCD-affine dispatch) ->
// the bucket's sd/cursor slices live in ONE XCD's L2; plain stores coalesce.
// Record: low32 = src*16, high32 = dst*16 (byte offsets into 16B-row tables).
__global__ __launch_bounds__(256) void scatter_kernel(
    const int* __restrict__ src, const int* __restrict__ dst,
    int* __restrict__ cursor, unsigned long long* __restrict__ sd,
    int E, int npb) {
    const int b = blockIdx.x & 7;
    const int gb = blockIdx.x >> 3;
    const int nbl = gridDim.x >> 3;
    const int lo = b * npb, hi = lo + npb;
    const int E4 = E >> 2;
    const int4* dst4 = (const int4*)dst;
    const int4* src4 = (const int4*)src;
    for (int i = gb * blockDim.x + threadIdx.x; i < E4; i += nbl * blockDim.x) {
        const int4 d = dst4[i];
        const int4 s = src4[i];
        if (d.x >= lo && d.x < hi) {
            const int p = atomicAdd(&cursor[d.x], 1);
            sd[p] = ((unsigned long long)(unsigned)(d.x << 4) << 32) | (unsigned)(s.x << 4);
        }
        if (d.y >= lo && d.y < hi) {
            const int p = atomicAdd(&cursor[d.y], 1);
            sd[p] = ((unsigned long long)(unsigned)(d.y << 4) << 32) | (unsigned)(s.y << 4);
        }
        if (d.z >= lo && d.z < hi) {
            const int p = atomicAdd(&cursor[d.z], 1);
            sd[p] = ((unsigned long long)(unsigned)(d.z << 4) << 32) | (unsigned)(s.z << 4);
        }
        if (d.w >= lo && d.w < hi) {
            const int p = atomicAdd(&cursor[d.w], 1);
            sd[p] = ((unsigned long long)(unsigned)(d.w << 4) << 32) | (unsigned)(s.w << 4);
        }
    }
    if (blockIdx.x == 0 && threadIdx.x < (E & 3)) {
        const int i = (E4 << 2) + threadIdx.x;
        const int d = dst[i];
        if (d >= lo && d < hi) {
            const int p = atomicAdd(&cursor[d], 1);
            sd[p] = ((unsigned long long)(unsigned)(d << 4) << 32) | (unsigned)(src[i] << 4);
        }
    }
}

// ---------------- per-edge softmax weights (fp16 pairs, u64 record) --------
// wq[i] = u64: low dword = half2(q_pos0,q_pos1), high dword = half2(q_pos2,q_pos3).
__global__ __launch_bounds__(256) void edge_w_kernel(
    const unsigned long long* __restrict__ sd,
    const float* __restrict__ asrc, const float* __restrict__ adst,
    const unsigned int* __restrict__ gmax, unsigned long long* __restrict__ wq,
    int Etot) {
    const char* aB = (const char*)asrc;
    const char* dB = (const char*)adst;
    const float g0 = fdec(gmax[0]), g1 = fdec(gmax[1]);
    const float g2 = fdec(gmax[2]), g3 = fdec(gmax[3]);
    for (int i = blockIdx.x * blockDim.x + threadIdx.x; i < Etot;
         i += gridDim.x * blockDim.x) {
        const unsigned long long rec = __builtin_nontemporal_load(&sd[i]);
        const unsigned s16 = (unsigned)rec;
        const unsigned d16 = (unsigned)(rec >> 32);
        const float4 as = *(const float4*)(aB + s16);
        const float4 ad = *(const float4*)(dB + d16);
        const float q0 = __expf(lrelu(as.x + ad.x) - lrelu(g0 + ad.x));
        const float q1 = __expf(lrelu(as.y + ad.y) - lrelu(g1 + ad.y));
        const float q2 = __expf(lrelu(as.z + ad.z) - lrelu(g2 + ad.z));
        const float q3 = __expf(lrelu(as.w + ad.w) - lrelu(g3 + ad.w));
        const unsigned lo = pack_h2(q0, q1);
        const unsigned hi = pack_h2(q2, q3);
        const unsigned long long out = ((unsigned long long)hi << 32) | lo;
        __builtin_nontemporal_store(out, &wq[i]);
    }
}

// ---------------- GEMM + alpha (+ fused hist + global head max) ----------------
// Hb layout (bf16): u16 idx = row*128 + (head&1)*64 + f*2 + (head>>1)
//   -> for lane (hp,f): one dword holds heads (hp, hp+2).
// asrc/adst layout: [row*4 + pos], pos(head) = [0,2,1,3] interleave.
template <int K>
__global__ __launch_bounds__(256) void gemm_hist(
    const float* __restrict__ X, const float* __restrict__ W,
    const float* __restrict__ AttS, const float* __restrict__ AttD,
    unsigned short* __restrict__ Hb, float* __restrict__ asrc, float* __restrict__ adst,
    unsigned int* __restrict__ gmax, int n, int gemmGrid,
    const int* __restrict__ dst, int* __restrict__ cnt, int E) {
    constexpr int KC = (K < 64) ? K : 64;
    __shared__ __align__(16) float Ws[KC * 128];
    __shared__ __align__(16) float Xs[32 * K];
    __shared__ unsigned int smax[4];
    const int tid = threadIdx.x;

    if (blockIdx.x >= gemmGrid) {
        // ---- hist role ----
        const int hb = blockIdx.x - gemmGrid;
        const int histBlocks = gridDim.x - gemmGrid;
        const int E4 = E >> 2;
        const int4* dst4 = (const int4*)dst;
        for (int i = hb * blockDim.x + tid; i < E4; i += histBlocks * blockDim.x) {
            const int4 d = dst4[i];
            atomicAdd(&cnt[d.x], 1);
            atomicAdd(&cnt[d.y], 1);
            atomicAdd(&cnt[d.z], 1);
            atomicAdd(&cnt[d.w], 1);
        }
        if (hb == 0 && tid < (E & 3)) atomicAdd(&cnt[dst[(E4 << 2) + tid]], 1);
        return;
    }

    // ---- gemm role ----
    const int r = tid >> 5;          // row-in-batch 0..7
    const int sub = tid & 31;
    const int c0 = sub * 4;          // output col base (0..124)
    const int head = sub >> 3;       // 0..3
    const int pos = ((head & 1) << 1) | (head >> 1);  // [0,2,1,3] order
    const int fc = (sub & 7) * 4;    // feat-in-head base
    const int rowBase = blockIdx.x * 32;

    if (tid < 4) smax[tid] = 0u;
    {
        const float4* X4 = (const float4*)X;
        float4* Xs4 = (float4*)Xs;
        const int K4 = K / 4;
        for (int i = tid; i < 32 * K4; i += 256) {
            int rr = rowBase + i / K4;
            Xs4[i] = (rr < n) ? X4[(size_t)rr * K4 + (i % K4)] : make_float4(0.f, 0.f, 0.f, 0.f);
        }
    }

    float acc[4][4] = {};
    for (int kt = 0; kt < K; kt += KC) {
        __syncthreads();
        {
            const float4* W4 = (const float4*)(W + kt * 128);
            float4* Ws4 = (float4*)Ws;
            for (int i = tid; i < KC * 32; i += 256) Ws4[i] = W4[i];
        }
        __syncthreads();
        for (int k = 0; k < KC; ++k) {
            const float4 wv = *(const float4*)&Ws[k * 128 + c0];
#pragma unroll
            for (int b = 0; b < 4; ++b) {
                float xv = Xs[(b * 8 + r) * K + kt + k];
                acc[b][0] = fmaf(xv, wv.x, acc[b][0]);
                acc[b][1] = fmaf(xv, wv.y, acc[b][1]);
                acc[b][2] = fmaf(xv, wv.z, acc[b][2]);
                acc[b][3] = fmaf(xv, wv.w, acc[b][3]);
            }
        }
    }

    float a_s[4], a_d[4];
#pragma unroll
    for (int j = 0; j < 4; ++j) {
        a_s[j] = AttS[head * 32 + fc + j];
        a_d[j] = AttD[head * 32 + fc + j];
    }
    // u16 index pieces: row*128 + (head&1)*64 + f*2 + (head>>1)
    const unsigned hbase_head = (unsigned)(head & 1) * 64 + (unsigned)(head >> 1) + fc * 2;
#pragma unroll
    for (int b = 0; b < 4; ++b) {
        const int row = rowBase + b * 8 + r;
        if (row < n) {
            const unsigned hbase = (unsigned)row * 128 + hbase_head;
            Hb[hbase + 0] = f2bf(acc[b][0]);
            Hb[hbase + 2] = f2bf(acc[b][1]);
            Hb[hbase + 4] = f2bf(acc[b][2]);
            Hb[hbase + 6] = f2bf(acc[b][3]);
            float ps = acc[b][0] * a_s[0] + acc[b][1] * a_s[1] +
                       acc[b][2] * a_s[2] + acc[b][3] * a_s[3];
            float pd = acc[b][0] * a_d[0] + acc[b][1] * a_d[1] +
                       acc[b][2] * a_d[2] + acc[b][3] * a_d[3];
#pragma unroll
            for (int msk = 1; msk < 8; msk <<= 1) {
                ps += __shfl_xor(ps, msk);
                pd += __shfl_xor(pd, msk);
            }
            if ((sub & 7) == 0) {
                asrc[row * 4 + pos] = ps;
                adst[row * 4 + pos] = pd;
                atomicMax(&smax[pos], fenc(ps));
            }
        }
    }
    __syncthreads();
    if (tid < 4) atomicMax(&gmax[tid], smax[tid]);
}

// ---------------- per-node aggregate (weights precomputed) ----------------
// One node per 64-lane group; lane = hp*32 + f owns heads (hp, hp+2) -> one
// Hb dword. Per edge: broadcast sd + weight dword, 1 gather, 2 fma.
__global__ __launch_bounds__(256) void node_kernel(
    const int* __restrict__ rowptr, const unsigned long long* __restrict__ sd,
    const unsigned short* __restrict__ Hb, const float* __restrict__ asrc,
    const float* __restrict__ adst, const unsigned int* __restrict__ gmax,
    const unsigned long long* __restrict__ wq, const float* __restrict__ bias,
    float* __restrict__ outp, int n, int apply_elu) {
    const int node = blockIdx.x * 4 + (threadIdx.x >> 6);
    if (node >= n) return;
    const int lane = threadIdx.x & 63;
    const unsigned f = lane & 31;
    const unsigned hp = lane >> 5;            // 0/1
    const unsigned hp8 = hp * 8;              // byte off into asrc/adst row (16B)
    const unsigned hp4 = hp * 4;              // byte off into wq record (8B)
    const unsigned hpf = hp * 128 + f * 4;    // byte off into Hb row (256B)
    const unsigned node16 = (unsigned)node * 16;
    const char* aB = (const char*)asrc;
    const char* dB = (const char*)adst;
    const char* hB = (const char*)Hb;
    const char* wB = (const char*)wq;

    const int beg = rowptr[node], end = rowptr[node + 1];
    const float2 ad01 = *(const float2*)(dB + node16 + hp8);
    const float2 M01 = make_float2(lrelu(fdec(gmax[hp * 2]) + ad01.x),
                                   lrelu(fdec(gmax[hp * 2 + 1]) + ad01.y));

    // self loop (fp32, same M as edge weights)
    const float2 aself = *(const float2*)(aB + node16 + hp8);
    float2 q = make_float2(__expf(lrelu(aself.x + ad01.x) - M01.x),
                           __expf(lrelu(aself.y + ad01.y) - M01.y));
    float2 s01 = q;
    const unsigned wSelf = *(const unsigned*)(hB + (node16 << 4) + hpf);
    float2 acc01 = make_float2(q.x * bflo(wSelf), q.y * bfhi(wSelf));

    int i = beg;
    for (; i + 16 <= end; i += 16) {
        unsigned sx[16];
#pragma unroll
        for (int u = 0; u < 16; ++u)
            sx[u] = (unsigned)__builtin_nontemporal_load(&sd[i + u]);  // low32 = s*16
        unsigned wv[16];
#pragma unroll
        for (int u = 0; u < 16; ++u)
            wv[u] = *(const unsigned*)(wB + (((unsigned)(i + u)) << 3) + hp4);
        unsigned w[16];
#pragma unroll
        for (int u = 0; u < 16; ++u) w[u] = *(const unsigned*)(hB + (sx[u] << 4) + hpf);
#pragma unroll
        for (int u = 0; u < 16; ++u) {
            const float2 qf = unpack_h2(wv[u]);
            s01.x += qf.x; s01.y += qf.y;
            acc01.x = fmaf(qf.x, bflo(w[u]), acc01.x);
            acc01.y = fmaf(qf.y, bfhi(w[u]), acc01.y);
        }
    }
    for (; i + 4 <= end; i += 4) {
        unsigned sx[4];
#pragma unroll
        for (int u = 0; u < 4; ++u)
            sx[u] = (unsigned)__builtin_nontemporal_load(&sd[i + u]);
        unsigned wv[4];
#pragma unroll
        for (int u = 0; u < 4; ++u)
            wv[u] = *(const unsigned*)(wB + (((unsigned)(i + u)) << 3) + hp4);
        unsigned w[4];
#pragma unroll
        for (int u = 0; u < 4; ++u) w[u] = *(const unsigned*)(hB + (sx[u] << 4) + hpf);
#pragma unroll
        for (int u = 0; u < 4; ++u) {
            const float2 qf = unpack_h2(wv[u]);
            s01.x += qf.x; s01.y += qf.y;
            acc01.x = fmaf(qf.x, bflo(w[u]), acc01.x);
            acc01.y = fmaf(qf.y, bfhi(w[u]), acc01.y);
        }
    }
    for (; i < end; ++i) {
        const unsigned sx = (unsigned)__builtin_nontemporal_load(&sd[i]);
        const unsigned wh = *(const unsigned*)(wB + (((unsigned)i) << 3) + hp4);
        const unsigned wv = *(const unsigned*)(hB + (sx << 4) + hpf);
        const float2 qf = unpack_h2(wh);
        s01.x += qf.x; s01.y += qf.y;
        acc01.x = fmaf(qf.x, bflo(wv), acc01.x);
        acc01.y = fmaf(qf.y, bfhi(wv), acc01.y);
    }

    float v = acc01.x / s01.x + acc01.y / s01.y;
    v += __shfl_xor(v, 32);     // add the other head pair
    v = v * 0.25f + bias[f];
    if (apply_elu) v = (v > 0.f) ? v : (__expf(v) - 1.f);
    if (lane < 32) outp[(size_t)node * 32 + f] = v;
}

// ---------------- launch ----------------

extern "C" void kernel_launch(void* const* d_in, const int* in_sizes, int n_in,
                              void* d_out, int out_size, void* d_ws, size_t ws_size,
                              hipStream_t stream) {
    const int N = in_sizes[0] / 128;
    const int E = in_sizes[1] / 2;
    const float* x = (const float*)d_in[0];
    const int* ei = (const int*)d_in[1];
    const float* W1 = (const float*)d_in[2];
    const float* atS1 = (const float*)d_in[3];
    const float* atD1 = (const float*)d_in[4];
    const float* b1 = (const float*)d_in[5];
    const float* W2 = (const float*)d_in[6];
    const float* atS2 = (const float*)d_in[7];
    const float* atD2 = (const float*)d_in[8];
    const float* b2 = (const float*)d_in[9];
    float* out = (float*)d_out;

    char* ws = (char*)d_ws;
    size_t off = 0;
    auto alloc = [&](size_t bytes) {
        void* p = ws + off;
        off = (off + bytes + 255) & ~(size_t)255;
        return p;
    };
    int* cnt = (int*)alloc((size_t)N * 4);
    unsigned int* gmax = (unsigned int*)alloc(8 * sizeof(unsigned int)); // [layer][pos]
    const size_t zeroBytes = off;  // cnt + gmax zeroed in one memset
    int* rowptr = (int*)alloc((size_t)(N + 1) * 4);
    int* cursor = (int*)alloc((size_t)N * 4);
    int* bsum = (int*)alloc(256 * 4);
    int* boff = (int*)alloc(256 * 4);
    unsigned long long* sd = (unsigned long long*)alloc((size_t)E * 8);
    unsigned long long* wq = (unsigned long long*)alloc((size_t)E * 8);
    unsigned short* hb = (unsigned short*)alloc((size_t)N * 128 * 2);  // packed bf16
    float* av_s = (float*)alloc((size_t)N * 4 * 4);
    float* av_d = (float*)alloc((size_t)N * 4 * 4);
    float* x2 = (float*)alloc((size_t)N * 32 * 4);

    const int* e_src = ei;
    const int* e_dst = ei + E;

    const int gemmGrid = (N + 31) / 32;
    const int histGrid = 1024;
    const int nodeGrid = (N + 3) / 4;
    const int npb = (N + 7) / 8;
    const int scanGrid = (N + 255) / 256;   // must be <= 256

    (void)hipMemsetAsync(cnt, 0, zeroBytes, stream);

    // layer 1
    gemm_hist<128><<<gemmGrid + histGrid, 256, 0, stream>>>(
        x, W1, atS1, atD1, hb, av_s, av_d, gmax, N, gemmGrid, e_dst, cnt, E);
    scan_part<<<scanGrid, 256, 0, stream>>>(cnt, bsum, N);
    scan_mid<<<1, 256, 0, stream>>>(bsum, boff, scanGrid, rowptr, N);
    scan_final<<<scanGrid, 256, 0, stream>>>(cnt, boff, rowptr, cursor, N);
    scatter_kernel<<<2048, 256, 0, stream>>>(e_src, e_dst, cursor, sd, E, npb);
    edge_w_kernel<<<2048, 256, 0, stream>>>(sd, av_s, av_d, gmax, wq, E);
    node_kernel<<<nodeGrid, 256, 0, stream>>>(rowptr, sd, hb, av_s, av_d, gmax,
                                              wq, b1, x2, N, 1);
    // layer 2
    gemm_hist<32><<<gemmGrid, 256, 0, stream>>>(
        x2, W2, atS2, atD2, hb, av_s, av_d, gmax + 4, N, gemmGrid, e_dst, cnt, E);
    edge_w_kernel<<<2048, 256, 0, stream>>>(sd, av_s, av_d, gmax + 4, wq, E);
    node_kernel<<<nodeGrid, 256, 0, stream>>>(rowptr, sd, hb, av_s, av_d, gmax + 4,
                                              wq, b2, out, N, 0);
}